// Round 5
// baseline (276.321 us; speedup 1.0000x reference)
//
#include <hip/hip_runtime.h>
#include <cstdint>

#define A_NUM 9
#define C_NUM 20
#define B_SZ 32
#define HW 784            // 28*28
#define P_NUM (A_NUM*HW)  // 7056
#define NBOX 64
#define CIN 1280
#define HID 128
#define M_IDX 4096
#define KSPLIT 2
#define ASTR 40           // padded A LDS row stride in bf16 elems (80 B)
#define PSTR ((size_t)B_SZ * HW * HID)   // floats between K-partials
#define IOU_PB 64         // p-rows per iou block
#define TP_HW 196
#define TP_S 197          // transpose LDS dword stride (2-way-free column reads)

// output layout (flat concat in return order)
#define CONF_OFF 0
#define OFFS_OFF (2*M_IDX)                 // 8192
#define CLS_OFF  (OFFS_OFF + 4*M_IDX)      // 24576
#define IOU_OFF  (CLS_OFF + C_NUM*M_IDX)   // 106496

typedef short bf16x8 __attribute__((ext_vector_type(8)));
typedef float f32x4  __attribute__((ext_vector_type(4)));

// round-half-up fp32->bf16, packed pair into one dword
__device__ __forceinline__ unsigned pack_bf16(float lo, float hi) {
  unsigned a = __builtin_bit_cast(unsigned, lo);
  unsigned b = __builtin_bit_cast(unsigned, hi);
  return ((a + 0x8000u) >> 16) | ((b + 0x8000u) & 0xffff0000u);
}

// ---- Transpose+pack: F fp32 [b][c][hw] -> Ft bf16 [b][hw][c] --------------
// Tile: 64 c x 196 hw. LDS holds bf16 c-pairs: T2[rp(32)][hw(196)] dwords.
__global__ __launch_bounds__(256) void transpose_pack(
    const float* __restrict__ F, unsigned* __restrict__ Ft) {
  __shared__ unsigned T2[32 * TP_S];
  const int b = blockIdx.z;
  const int cc = blockIdx.y;      // 0..19 -> c0 = cc*64
  const int hc = blockIdx.x;      // 0..3  -> hw0 = hc*196
  const int t = threadIdx.x;
  const int c0 = cc * 64, hw0 = hc * TP_HW;
  const float* Fb = F + ((size_t)b * CIN + c0) * HW + hw0;
  // read: 1568 slots = 32 row-pairs x 49 chunks of 4 hw (fully coalesced)
  for (int i = 0; i < 7; i++) {
    int slot = t + 256 * i;
    if (slot < 1568) {
      int rp = slot / 49, ch = slot - rp * 49;
      const float* s0 = Fb + (size_t)(2 * rp) * HW + ch * 4;
      float4 lo4 = *(const float4*)s0;
      float4 hi4 = *(const float4*)(s0 + HW);
      unsigned* d = &T2[rp * TP_S + ch * 4];
      d[0] = pack_bf16(lo4.x, hi4.x);
      d[1] = pack_bf16(lo4.y, hi4.y);
      d[2] = pack_bf16(lo4.z, hi4.z);
      d[3] = pack_bf16(lo4.w, hi4.w);
    }
  }
  __syncthreads();
  // write: 3136 ids = 196 hw x 16 chunks of 8B (128 B contiguous per 16 lanes)
  unsigned* Fo = Ft + ((size_t)b * HW + hw0) * (CIN / 2) + c0 / 2;
  for (int i = 0; i < 13; i++) {
    int id = t + 256 * i;
    if (id < 3136) {
      int hw = id >> 4, ch = id & 15;
      uint2 v;
      v.x = T2[(2 * ch) * TP_S + hw];
      v.y = T2[(2 * ch + 1) * TP_S + hw];
      *(uint2*)&Fo[(size_t)hw * (CIN / 2) + ch * 2] = v;
    }
  }
}

// ---- W1 prep: fp32 [n][c] -> bf16 in MFMA B-fragment order ----------------
// layout: [ks(40)][ntile(8)][lane(64)][k8]
__global__ __launch_bounds__(256) void prep_w1(const float* __restrict__ W1,
                                               uint4* __restrict__ W1f) {
  int id = blockIdx.x * 256 + threadIdx.x;
  int lane = id & 63;
  int ntile = (id >> 6) & 7;
  int ks = id >> 9;                         // 0..39
  int lo = lane & 15, quad = lane >> 4;
  int n = ntile * 16 + lo;
  int k0 = ks * 32 + quad * 8;
  const float* src = W1 + n * CIN + k0;
  float4 x = *(const float4*)src;
  float4 y = *(const float4*)(src + 4);
  uint4 p;
  p.x = pack_bf16(x.x, x.y);
  p.y = pack_bf16(x.z, x.w);
  p.z = pack_bf16(y.x, y.y);
  p.w = pack_bf16(y.z, y.w);
  W1f[id] = p;
}

// ---- Layer-1 GEMM via MFMA from pre-transposed Ft, KSPLIT=2 ----------------
// Part[z][b][m][n] = sum_{c in z-half} Ft[b][m][c] * W1[n][c]
__global__ __launch_bounds__(256) void gemm1_mfma(
    const unsigned short* __restrict__ Ft, const unsigned short* __restrict__ W1f,
    float* __restrict__ Part) {
  __shared__ unsigned short Asm[2][64 * ASTR];

  const int b = blockIdx.y, z = blockIdx.z;
  const int m0 = blockIdx.x * 64;
  const int t = threadIdx.x;
  const int wave = t >> 6, lane = t & 63;
  const int quad = lane >> 4, lo = lane & 15;
  const int sm = t >> 2, kc = t & 3;   // staging: 16B chunk (m=sm, k=kc*8)
  const int gm = m0 + sm;
  const unsigned short* Fr =
      Ft + ((size_t)b * HW + (gm < HW ? gm : 0)) * CIN + z * 640;

  f32x4 acc[4][2];
#pragma unroll
  for (int i = 0; i < 4; i++)
#pragma unroll
    for (int j = 0; j < 2; j++) acc[i][j] = (f32x4){0.f, 0.f, 0.f, 0.f};

  uint4 va;
  uint4 vb[2][2];

  auto loadA = [&](int kk) { va = *(const uint4*)(Fr + kk * 32 + kc * 8); };
  auto loadB = [&](int kk, uint4* dst) {
    const unsigned short* g =
        W1f + (size_t)((((z * 20 + kk) * 8) + wave * 2) * 64 + lane) * 8;
    dst[0] = *(const uint4*)g;
    dst[1] = *(const uint4*)(g + 512);
  };
  auto stageA = [&](int buf) {
    *(uint4*)&Asm[buf][sm * ASTR + kc * 8] = va;
  };
  auto compute = [&](int buf, uint4* bv) {
    const unsigned short* Ab = &Asm[buf][lo * ASTR + quad * 8];
    bf16x8 af[4];
#pragma unroll
    for (int i = 0; i < 4; i++) af[i] = *(const bf16x8*)(Ab + i * 16 * ASTR);
    bf16x8 b0 = __builtin_bit_cast(bf16x8, bv[0]);
    bf16x8 b1 = __builtin_bit_cast(bf16x8, bv[1]);
#pragma unroll
    for (int i = 0; i < 4; i++) {
      acc[i][0] = __builtin_amdgcn_mfma_f32_16x16x32_bf16(af[i], b0, acc[i][0], 0, 0, 0);
      acc[i][1] = __builtin_amdgcn_mfma_f32_16x16x32_bf16(af[i], b1, acc[i][1], 0, 0, 0);
    }
  };

  loadA(0);
  loadB(0, vb[0]);
  stageA(0);
  __syncthreads();
  for (int kk = 0; kk < 20; kk++) {
    const int cur = kk & 1;
    if (kk + 1 < 20) {
      loadA(kk + 1);
      loadB(kk + 1, vb[cur ^ 1]);
    }
    compute(cur, vb[cur]);
    if (kk + 1 < 20) stageA(cur ^ 1);
    __syncthreads();
  }

  float* Pz = Part + ((size_t)(z * B_SZ + b) * HW) * HID;
#pragma unroll
  for (int i = 0; i < 4; i++) {
    const int mbase = m0 + i * 16 + quad * 4;
#pragma unroll
    for (int j = 0; j < 2; j++) {
      const int n = wave * 32 + j * 16 + lo;
#pragma unroll
      for (int r = 0; r < 4; r++) {
        const int mm = mbase + r;
        if (mm < HW) Pz[(size_t)mm * HID + n] = acc[i][j][r];
      }
    }
  }
}

// ---- IoU: 64 p-rows x 64 boxes per block, 16 outputs/thread ---------------
__global__ __launch_bounds__(256) void iou_kernel(
    const float* __restrict__ grid, const float* __restrict__ anc,
    const float* __restrict__ bboxes, float* __restrict__ out) {
  __shared__ float sb[NBOX * 5];
  __shared__ float4 sp4[IOU_PB];
  const int b = blockIdx.y;
  const int p0 = blockIdx.x * IOU_PB;
  const int t = threadIdx.x;
  for (int i = t; i < NBOX * 5; i += 256) sb[i] = bboxes[b * NBOX * 5 + i];
  if (t < IOU_PB) {
    int p = p0 + t;
    float x1 = 0.f, y1 = 0.f, x2 = 0.f, y2 = 0.f;
    if (p < P_NUM) {
      int a = p / HW, hw = p - a * HW;
      float2 c = ((const float2*)grid)[b * HW + hw];
      float hx = anc[a * 2 + 0] * 0.5f, hy = anc[a * 2 + 1] * 0.5f;
      x1 = c.x - hx; y1 = c.y - hy; x2 = c.x + hx; y2 = c.y + hy;
    }
    sp4[t] = make_float4(x1, y1, x2, y2);
  }
  __syncthreads();
  const int nl = (t & 15) * 4;
  const int pi = t >> 4;
#pragma unroll
  for (int ip = 0; ip < 4; ip++) {
    const int pl = pi + 16 * ip;
    const int p = p0 + pl;
    const float4 pb = sp4[pl];
    const float spA = (pb.z - pb.x) * (pb.w - pb.y);
    float4 res;
#pragma unroll
    for (int jn = 0; jn < 4; jn++) {
      const int n = nl + jn;
      float bx1 = sb[n * 5 + 0], by1 = sb[n * 5 + 1];
      float bx2 = sb[n * 5 + 2], by2 = sb[n * 5 + 3];
      float s_b = (bx2 - bx1) * (by2 - by1);
      float ix1 = fmaxf(pb.x, bx1), iy1 = fmaxf(pb.y, by1);
      float ix2 = fminf(pb.z, bx2), iy2 = fminf(pb.w, by2);
      float si = fmaxf(ix2 - ix1, 0.f) * fmaxf(iy2 - iy1, 0.f);
      float su = spA + s_b - si;
      float iou = fmaxf(si / (su + 1e-8f), 0.f);
      bool invalid = (su <= 0.f) | (spA <= 0.f) | (s_b <= 0.f) | (bx1 < 0.f);
      float v = invalid ? 0.f : iou;
      if (jn == 0) res.x = v; else if (jn == 1) res.y = v;
      else if (jn == 2) res.z = v; else res.w = v;
    }
    if (p < P_NUM)
      *(float4*)&out[((size_t)(b * P_NUM + p)) * 64 + nl] = res;
  }
}

// ---- Gathered layer-2 head: 4 indices per block (one per wave) -------------
__global__ __launch_bounds__(256) void gather_kernel(
    const int* __restrict__ pos_idx, const int* __restrict__ neg_idx,
    const float* __restrict__ Part, const float* __restrict__ b1,
    const float* __restrict__ W2, const float* __restrict__ b2,
    float* __restrict__ out) {
  __shared__ float sh[4][HID];
  const int sub = threadIdx.x >> 6;
  const int l = threadIdx.x & 63;
  const int blk = blockIdx.x * 4 + sub;
  const bool pos = blk < M_IDX;
  const int idx = pos ? pos_idx[blk] : neg_idx[blk - M_IDX];
  const int b = idx / P_NUM;
  const int r = idx - b * P_NUM;
  const int a = r / HW;
  const int hw = r - a * HW;
  const float2* row = (const float2*)(Part + ((size_t)(b * HW + hw)) * HID) + l;
  float2 s0 = row[0];
  float2 s1 = row[PSTR / 2];
  float v0 = s0.x + s1.x + b1[2 * l];
  float v1 = s0.y + s1.y + b1[2 * l + 1];
  v0 = v0 > 0.f ? v0 : 0.01f * v0;
  v1 = v1 > 0.f ? v1 : 0.01f * v1;
  sh[sub][2 * l] = v0; sh[sub][2 * l + 1] = v1;
  __syncthreads();
  if (pos) {
    if (l < 25) {
      int o = (l < 5) ? (a * 5 + l) : (5 * A_NUM + (l - 5));
      const float* w = W2 + o * HID;
      float dot = b2[o];
#pragma unroll 8
      for (int k = 0; k < HID; k++) dot = fmaf(w[k], sh[sub][k], dot);
      if (l == 0) {
        out[CONF_OFF + blk] = 1.f / (1.f + expf(-dot));
      } else if (l < 3) {
        out[OFFS_OFF + blk * 4 + (l - 1)] = 1.f / (1.f + expf(-dot)) - 0.5f;
      } else if (l < 5) {
        out[OFFS_OFF + blk * 4 + (l - 1)] = dot;
      } else {
        out[CLS_OFF + blk * C_NUM + (l - 5)] = dot;
      }
    }
  } else {
    int o = a * 5;
    const float* w = W2 + o * HID;
    float part = fmaf(w[2 * l], v0, w[2 * l + 1] * v1);
#pragma unroll
    for (int off = 32; off > 0; off >>= 1) part += __shfl_down(part, off);
    if (l == 0) out[CONF_OFF + blk] = 1.f / (1.f + expf(-(b2[o] + part)));
  }
}

extern "C" void kernel_launch(void* const* d_in, const int* in_sizes, int n_in,
                              void* d_out, int out_size, void* d_ws, size_t ws_size,
                              hipStream_t stream) {
  const float* features = (const float*)d_in[0];
  const float* grid     = (const float*)d_in[1];
  const float* anc      = (const float*)d_in[2];
  const float* bboxes   = (const float*)d_in[3];
  const int*   pos_idx  = (const int*)d_in[4];
  const int*   neg_idx  = (const int*)d_in[5];
  const float* W1       = (const float*)d_in[6];
  const float* b1       = (const float*)d_in[7];
  const float* W2       = (const float*)d_in[8];
  const float* b2       = (const float*)d_in[9];
  float* out = (float*)d_out;

  // ws layout: W1f 327,680 B | Ft bf16 32*784*1280*2 = 64,225,280 B | Part fp32 x2
  uint4* W1f = (uint4*)d_ws;
  unsigned* Ft = (unsigned*)((char*)d_ws + 327680);
  float* Part = (float*)((char*)d_ws + 327680 + 64225280);

  hipLaunchKernelGGL(transpose_pack, dim3(4, 20, B_SZ), dim3(256), 0, stream,
                     features, Ft);
  hipLaunchKernelGGL(prep_w1, dim3(80), dim3(256), 0, stream, W1, W1f);
  hipLaunchKernelGGL(gemm1_mfma, dim3(13, B_SZ, KSPLIT), dim3(256), 0, stream,
                     (const unsigned short*)Ft, (const unsigned short*)W1f, Part);
  hipLaunchKernelGGL(iou_kernel, dim3((P_NUM + IOU_PB - 1) / IOU_PB, B_SZ),
                     dim3(256), 0, stream, grid, anc, bboxes, out + IOU_OFF);
  hipLaunchKernelGGL(gather_kernel, dim3(2 * M_IDX / 4), dim3(256),
                     0, stream, pos_idx, neg_idx, Part, b1, W2, b2, out);
}